// Round 14
// baseline (266.123 us; speedup 1.0000x reference)
//
#include <hip/hip_runtime.h>
#include <hip/hip_bf16.h>

#define F_IN 128

typedef short bf16x8 __attribute__((ext_vector_type(8)));
typedef short bf16x4 __attribute__((ext_vector_type(4)));
typedef float f32x4  __attribute__((ext_vector_type(4)));
typedef float f32x2  __attribute__((ext_vector_type(2)));

// ---------------- W -> fragment-major bf16 repack helper ----------------
// lane l holds W[k = kt*32 + (l>>4)*4 + (j&3) + 16*(j>>2)][col = nt*16 + (l&15)]

template <int KT, int NT>
__device__ inline void prep_w_one(const float* __restrict__ W, ushort* __restrict__ WF,
                                  int tid) {
  int l  = tid & 63;
  int nt = (tid >> 6) % NT;
  int kt = tid / (64 * NT);
  int colc = nt * 16 + (l & 15);
  int kbase = kt * 32 + (l >> 4) * 4;
  ushort v[8];
  #pragma unroll
  for (int j = 0; j < 8; ++j) {
    int k = kbase + (j & 3) + 16 * (j >> 2);
    __hip_bfloat16 h = __float2bfloat16(W[(size_t)k * (NT * 16) + colc]);
    v[j] = *(ushort*)&h;
  }
  uint4 pk;
  pk.x = (uint)v[0] | ((uint)v[1] << 16);
  pk.y = (uint)v[2] | ((uint)v[3] << 16);
  pk.z = (uint)v[4] | ((uint)v[5] << 16);
  pk.w = (uint)v[6] | ((uint)v[7] << 16);
  *(uint4*)(WF + (size_t)tid * 8) = pk;
}

// ---------------- fused: bf16-convert + edge count + weight repack ----------------
// cnt must be zeroed (hipMemsetAsync) before this kernel.

__global__ void k_prep(const float* __restrict__ X, const int* __restrict__ l2g,
                       const int* __restrict__ dst, ushort* __restrict__ xsub,
                       int* __restrict__ cnt,
                       const float* __restrict__ W1, const float* __restrict__ W2,
                       ushort* __restrict__ w1f, ushort* __restrict__ w2f,
                       int n32, int E) {
  int i = blockIdx.x * blockDim.x + threadIdx.x;
  if (i < 4096) prep_w_one<4, 16>(W1, w1f, i);
  else if (i < 8192) prep_w_one<8, 8>(W2, w2f, i - 4096);
  if (i < E) atomicAdd(&cnt[dst[i]], 1);
  if (i < n32) {
    int row = i >> 5, c4 = (i & 31) * 4;
    int g = l2g[row];
    float4 v = *(const float4*)(X + (size_t)g * 128 + c4);
    ushort o[4];
    __hip_bfloat16 h;
    h = __float2bfloat16(v.x); o[0] = *(ushort*)&h;
    h = __float2bfloat16(v.y); o[1] = *(ushort*)&h;
    h = __float2bfloat16(v.z); o[2] = *(ushort*)&h;
    h = __float2bfloat16(v.w); o[3] = *(ushort*)&h;
    uint2 pk;
    pk.x = (uint)o[0] | ((uint)o[1] << 16);
    pk.y = (uint)o[2] | ((uint)o[3] << 16);
    *(uint2*)(xsub + (size_t)row * 128 + c4) = pk;
  }
}

// ---------------- CSR scans (ordered; row size = cnt + 1, self-loop at slot 0) --------

__global__ void k_scan1(const int* __restrict__ cnt, int* __restrict__ rp,
                        int* __restrict__ bsum, float* __restrict__ dis,
                        int* __restrict__ fill, int n) {
  int tid = threadIdx.x;
  int i = blockIdx.x * 256 + tid;
  int v = (i < n) ? cnt[i] + 1 : 0;       // + self-loop
  int orig = v;
  int lane = tid & 63;
  #pragma unroll
  for (int d = 1; d < 64; d <<= 1) {
    int t = __shfl_up(v, d);
    if (lane >= d) v += t;
  }
  __shared__ int wsum[4];
  int wid = tid >> 6;
  if (lane == 63) wsum[wid] = v;
  __syncthreads();
  int off = 0;
  for (int w = 0; w < wid; ++w) off += wsum[w];
  int incl = v + off;
  if (i < n) {
    rp[i]   = incl - orig;
    dis[i]  = rsqrtf((float)orig);
    fill[i] = 1;                          // slot 0 reserved for self
  }
  if (tid == 255) bsum[blockIdx.x] = incl;
}

__global__ void k_scan2(int* __restrict__ bsum, int nb) {
  __shared__ int s[1024];
  int tid = threadIdx.x;
  int v = (tid < nb) ? bsum[tid] : 0;
  s[tid] = v;
  __syncthreads();
  for (int d = 1; d < 1024; d <<= 1) {
    int t = (tid >= d) ? s[tid - d] : 0;
    __syncthreads();
    s[tid] += t;
    __syncthreads();
  }
  if (tid < nb) bsum[tid] = s[tid] - v;
}

__global__ void k_scan3(int* __restrict__ rp, const int* __restrict__ bsum, int n, int Etot) {
  int i = blockIdx.x * blockDim.x + threadIdx.x;
  if (i < n) rp[i] += bsum[i >> 8];
  if (i == 0) rp[n] = Etot;
}

// edges at slots >=1; self (i, dis_i^2) at slot 0; also pre-fills the output tensor
__global__ void k_fill_csr(const int* __restrict__ src, const int* __restrict__ dst,
                           const int* __restrict__ rp, int* __restrict__ fill,
                           const float* __restrict__ dis,
                           int2* __restrict__ cw, float* __restrict__ out,
                           int E, int n, int outtot) {
  int e = blockIdx.x * blockDim.x + threadIdx.x;
  if (e < outtot) out[e] = -0.69314718055994531f;   // log(1/2)
  if (e < n) {
    float d = dis[e];
    cw[rp[e]] = make_int2(e, __float_as_int(d * d));
  }
  if (e < E) {
    int s = src[e], d = dst[e];
    int pos = rp[d] + atomicAdd(&fill[d], 1);
    cw[pos] = make_int2(s, __float_as_int(dis[s] * dis[d]));
  }
}

// ---------------- aggregation: 4 groups x 16 lanes x 16B, 16-deep gather pipeline -----
// One wave per node; the node's contiguous cw row sits in registers (lane i = slot i);
// per-slot (s,w) come from __shfl broadcasts. One round covers 16 slots: 4 masked
// gathers per group issued back-to-back BEFORE any FMA. p-blocks fully beyond the
// node's degree are skipped with a WAVE-UNIFORM branch (deg is wave-uniform).
// FUSEW3 folds the 128x2 GEMM into the epilogue (writes h3[2] instead of the row).

template <bool BIASRELU, bool FUSEW3>
__global__ void k_aggb(const ushort* __restrict__ X, const int* __restrict__ rp,
                       const int2* __restrict__ cw, const float* __restrict__ bias,
                       const float* __restrict__ W3,
                       ushort* __restrict__ outp, float* __restrict__ h3, int n) {
  int wavei = (int)((blockIdx.x * (size_t)blockDim.x + threadIdx.x) >> 6);
  int lane = threadIdx.x & 63;
  if (wavei >= n) return;
  int q = lane >> 4, ln = lane & 15;
  int e0 = rp[wavei], deg = rp[wavei + 1] - e0;  // >= 1 (self at slot 0)
  int dmax = deg < 64 ? deg : 64;

  // whole edge row in registers: lane i holds slot i (coalesced single load)
  int2 cme = make_int2(0, 0);
  if (lane < dmax) cme = cw[e0 + lane];

  f32x2 acc[4];
  #pragma unroll
  for (int j = 0; j < 4; ++j) acc[j] = f32x2{0.f, 0.f};

  for (int t0 = 0; t0 < dmax; t0 += 16) {
    uint4 r[4];
    float wv[4];
    bool  m[4];
    #pragma unroll
    for (int p = 0; p < 4; ++p) {
      if (t0 + p * 4 < dmax) {                     // wave-uniform skip
        int t = t0 + p * 4 + q;
        m[p] = t < dmax;
        int ts = t & 63;
        int  s = __shfl(cme.x, ts);
        wv[p]  = __int_as_float(__shfl(cme.y, ts));
        r[p] = make_uint4(0u, 0u, 0u, 0u);
        if (m[p]) r[p] = *(const uint4*)((const char*)X + (((uint)s << 8) + ((uint)ln << 4)));
      } else {
        m[p] = false;
      }
    }
    #pragma unroll
    for (int p = 0; p < 4; ++p) {
      if (t0 + p * 4 < dmax) {                     // wave-uniform skip
        if (m[p]) {
          uint u[4] = {r[p].x, r[p].y, r[p].z, r[p].w};
          f32x2 wvv = {wv[p], wv[p]};
          #pragma unroll
          for (int tt = 0; tt < 4; ++tt) {
            f32x2 v;
            v.x = __uint_as_float(u[tt] << 16);
            v.y = __uint_as_float(u[tt] & 0xffff0000u);
            acc[tt] += wvv * v;
          }
        }
      }
    }
  }

  // rare tail: deg > 64 (direct cw reads)
  for (int t0 = 64; t0 < deg; t0 += 4) {
    int t = t0 + q;
    if (t < deg) {
      int2 c = cw[e0 + t];
      float w = __int_as_float(c.y);
      uint4 r = *(const uint4*)((const char*)X + (((uint)c.x << 8) + ((uint)ln << 4)));
      uint u[4] = {r.x, r.y, r.z, r.w};
      f32x2 wvv = {w, w};
      #pragma unroll
      for (int tt = 0; tt < 4; ++tt) {
        f32x2 v;
        v.x = __uint_as_float(u[tt] << 16);
        v.y = __uint_as_float(u[tt] & 0xffff0000u);
        acc[tt] += wvv * v;
      }
    }
  }

  // reduce across the 4 groups (lane bits 4,5)
  #pragma unroll
  for (int j = 0; j < 4; ++j) {
    acc[j].x += __shfl_xor(acc[j].x, 16);
    acc[j].y += __shfl_xor(acc[j].y, 16);
    acc[j].x += __shfl_xor(acc[j].x, 32);
    acc[j].y += __shfl_xor(acc[j].y, 32);
  }

  if (lane < 16) {
    if (BIASRELU) {
      float4 b0 = *(const float4*)(bias + ln * 8);
      float4 b1 = *(const float4*)(bias + ln * 8 + 4);
      acc[0].x = fmaxf(acc[0].x + b0.x, 0.f);
      acc[0].y = fmaxf(acc[0].y + b0.y, 0.f);
      acc[1].x = fmaxf(acc[1].x + b0.z, 0.f);
      acc[1].y = fmaxf(acc[1].y + b0.w, 0.f);
      acc[2].x = fmaxf(acc[2].x + b1.x, 0.f);
      acc[2].y = fmaxf(acc[2].y + b1.y, 0.f);
      acc[3].x = fmaxf(acc[3].x + b1.z, 0.f);
      acc[3].y = fmaxf(acc[3].y + b1.w, 0.f);
    }
    if (FUSEW3) {
      const float4* w3p = (const float4*)(W3 + ln * 16);
      float p0 = 0.f, p1 = 0.f;
      #pragma unroll
      for (int j2 = 0; j2 < 4; ++j2) {
        float4 wa = w3p[j2];
        p0 = fmaf(acc[j2].x, wa.x, p0);
        p1 = fmaf(acc[j2].x, wa.y, p1);
        p0 = fmaf(acc[j2].y, wa.z, p0);
        p1 = fmaf(acc[j2].y, wa.w, p1);
      }
      p0 += __shfl_xor(p0, 1); p1 += __shfl_xor(p1, 1);
      p0 += __shfl_xor(p0, 2); p1 += __shfl_xor(p1, 2);
      p0 += __shfl_xor(p0, 4); p1 += __shfl_xor(p1, 4);
      p0 += __shfl_xor(p0, 8); p1 += __shfl_xor(p1, 8);
      if (ln == 0) {
        float2 rr = make_float2(p0, p1);
        *(float2*)(h3 + (size_t)wavei * 2) = rr;
      }
    } else {
      uint pk[4];
      #pragma unroll
      for (int j2 = 0; j2 < 4; ++j2) {
        __hip_bfloat16 hx = __float2bfloat16(acc[j2].x);
        __hip_bfloat16 hy = __float2bfloat16(acc[j2].y);
        pk[j2] = (uint)(*(ushort*)&hx) | ((uint)(*(ushort*)&hy) << 16);
      }
      uint4 sv = make_uint4(pk[0], pk[1], pk[2], pk[3]);
      *(uint4*)((char*)outp + (((size_t)wavei << 8) + ((uint)ln << 4))) = sv;
    }
  }
}

// ---------------- FUSED GEMM1+GEMM2: xt[n,128] -> h2 = relu(xt@W1+b1)@W2 -> bf16 ------
// Block = 256 threads (4 waves), BM = 128 rows.
// gemm1: wave w owns output cols [w*64, w*64+64) (W1 frags in registers).
// Handoff: those cols ARE gemm2's k-slice (k-tiles 2w, 2w+1); the gemm1 output
// fragment layout equals the gemm2 A-fragment layout.
// gemm2: each wave computes a 16x128 partial (its k-slice) per row-subtile;
// partials summed across the 4 waves via XOR-swizzled LDS, stored bf16.

__global__ __launch_bounds__(256) void k_gemm12(const ushort* __restrict__ A,
                                                const ushort* __restrict__ WF1,
                                                const ushort* __restrict__ WF2,
                                                const float* __restrict__ bias1,
                                                ushort* __restrict__ H2, int n) {
  __shared__ short stage[128 * 128];       // 32 KB bf16 input tile
  __shared__ float red[4][16][128];        // 32 KB f32 partial-sum buffer

  int tid = threadIdx.x;
  int r0 = blockIdx.x * 128;
  int l  = tid & 63;
  int w  = tid >> 6;
  int hi = l >> 4;

  // W1 fragments for this wave's N-slice (cols w*64..w*64+63): nt = w*4..w*4+3
  bf16x8 wreg1[16];
  #pragma unroll
  for (int kt = 0; kt < 4; ++kt)
    #pragma unroll
    for (int nt = 0; nt < 4; ++nt)
      wreg1[kt * 4 + nt] =
          *(const bf16x8*)(WF1 + ((size_t)(kt * 16 + w * 4 + nt) * 64 + l) * 8);

  // W2 fragments for this wave's k-slice (k-tiles 2w, 2w+1), all 8 n-tiles
  bf16x8 wreg2[16];
  #pragma unroll
  for (int kt2 = 0; kt2 < 2; ++kt2)
    #pragma unroll
    for (int nt2 = 0; nt2 < 8; ++nt2)
      wreg2[kt2 * 8 + nt2] =
          *(const bf16x8*)(WF2 + ((size_t)((w * 2 + kt2) * 8 + nt2) * 64 + l) * 8);

  // bias1 for this wave's col slice
  float bb[4][4];
  #pragma unroll
  for (int nt = 0; nt < 4; ++nt) {
    float4 b4 = *(const float4*)(bias1 + (w * 4 + nt) * 16 + hi * 4);
    bb[nt][0] = b4.x; bb[nt][1] = b4.y; bb[nt][2] = b4.z; bb[nt][3] = b4.w;
  }

  // stage xt tile (coalesced 16B loads, XOR-swizzled 16B chunks; 16 chunks/row)
  #pragma unroll
  for (int p = 0; p < 8; ++p) {
    int idx = p * 256 + tid;
    int row = idx >> 4, c = idx & 15;
    uint4 v = make_uint4(0u, 0u, 0u, 0u);
    if (r0 + row < n) v = *(const uint4*)(A + (size_t)(r0 + row) * 128 + c * 8);
    *(uint4*)(&stage[row * 128 + ((c ^ (row & 15)) * 8)]) = v;
  }
  __syncthreads();

  int sw = l & 15;
  for (int s = 0; s < 8; ++s) {
    int rowl = s * 16 + (l & 15);
    // gemm1 X-fragments from LDS
    bf16x8 xf[4];
    #pragma unroll
    for (int kt = 0; kt < 4; ++kt) {
      int c0 = kt * 4 + (hi >> 1);
      int within = (hi & 1) * 4;
      bf16x4 lo = *(const bf16x4*)(&stage[rowl * 128 + (c0 ^ sw) * 8 + within]);
      bf16x4 hx = *(const bf16x4*)(&stage[rowl * 128 + ((c0 + 2) ^ sw) * 8 + within]);
      bf16x8 a;
      a[0] = lo[0]; a[1] = lo[1]; a[2] = lo[2]; a[3] = lo[3];
      a[4] = hx[0]; a[5] = hx[1]; a[6] = hx[2]; a[7] = hx[3];
      xf[kt] = a;
    }

    // gemm1: 16 MFMAs -> acc[nt][r] = h1[row][ (w*4+nt)*16 + hi*4 + r ]
    f32x4 acc[4];
    #pragma unroll
    for (int nt = 0; nt < 4; ++nt) acc[nt] = f32x4{0.f, 0.f, 0.f, 0.f};
    #pragma unroll
    for (int nt = 0; nt < 4; ++nt)
      #pragma unroll
      for (int kt = 0; kt < 4; ++kt)
        acc[nt] = __builtin_amdgcn_mfma_f32_16x16x32_bf16(wreg1[kt * 4 + nt], xf[kt],
                                                          acc[nt], 0, 0, 0);

    // bias + relu + pack: gemm1 output frags ARE gemm2 A-frags for k-tiles 2w,2w+1
    bf16x8 xf2[2];
    #pragma unroll
    for (int kt2 = 0; kt2 < 2; ++kt2) {
      bf16x8 t;
      #pragma unroll
      for (int j = 0; j < 8; ++j) {
        int nt = kt2 * 2 + (j >> 2), r = j & 3;
        float v = fmaxf(acc[nt][r] + bb[nt][r], 0.0f);
        __hip_bfloat16 h = __float2bfloat16(v);
        t[j] = *(short*)&h;
      }
      xf2[kt2] = t;
    }

    // gemm2 partial: 16 MFMAs over this wave's k-slice
    f32x4 acc2[8];
    #pragma unroll
    for (int nt2 = 0; nt2 < 8; ++nt2) acc2[nt2] = f32x4{0.f, 0.f, 0.f, 0.f};
    #pragma unroll
    for (int nt2 = 0; nt2 < 8; ++nt2)
      #pragma unroll
      for (int kt2 = 0; kt2 < 2; ++kt2)
        acc2[nt2] = __builtin_amdgcn_mfma_f32_16x16x32_bf16(wreg2[kt2 * 8 + nt2], xf2[kt2],
                                                            acc2[nt2], 0, 0, 0);

    // write partials to LDS (XOR-swizzled: col ^= (row&7)<<2)
    int prow = l & 15;
    #pragma unroll
    for (int nt2 = 0; nt2 < 8; ++nt2) {
      int col = nt2 * 16 + hi * 4;
      int cs = col ^ ((prow & 7) << 2);
      *(f32x4*)(&red[w][prow][cs]) = acc2[nt2];
    }
    __syncthreads();

    // reduce across 4 waves; store bf16 h2 rows
    #pragma unroll
    for (int gi = 0; gi < 2; ++gi) {
      int g = tid * 2 + gi;
      int row = g >> 5, c4 = (g & 31) * 4;
      int cs = c4 ^ ((row & 7) << 2);
      f32x4 s0 = *(const f32x4*)(&red[0][row][cs]);
      f32x4 s1 = *(const f32x4*)(&red[1][row][cs]);
      f32x4 s2 = *(const f32x4*)(&red[2][row][cs]);
      f32x4 s3 = *(const f32x4*)(&red[3][row][cs]);
      f32x4 sm = s0 + s1 + s2 + s3;
      int grow = r0 + s * 16 + row;
      if (grow < n) {
        ushort o[4];
        __hip_bfloat16 h;
        h = __float2bfloat16(sm[0]); o[0] = *(ushort*)&h;
        h = __float2bfloat16(sm[1]); o[1] = *(ushort*)&h;
        h = __float2bfloat16(sm[2]); o[2] = *(ushort*)&h;
        h = __float2bfloat16(sm[3]); o[3] = *(ushort*)&h;
        uint2 pk;
        pk.x = (uint)o[0] | ((uint)o[1] << 16);
        pk.y = (uint)o[2] | ((uint)o[3] << 16);
        *(uint2*)(H2 + (size_t)grow * 128 + c4) = pk;
      }
    }
    __syncthreads();
  }
}

// ---------------- final: aggregate h3 + bias + log_softmax scatter ----------------

__global__ void k_agg3(const float* __restrict__ h3, const int* __restrict__ rp,
                       const int2* __restrict__ cw, const float* __restrict__ b3,
                       const int* __restrict__ l2g, float* __restrict__ out, int n) {
  int i = blockIdx.x * blockDim.x + threadIdx.x;
  if (i >= n) return;
  float a0 = 0.f, a1 = 0.f;
  int e0 = rp[i], e1 = rp[i + 1];
  for (int e = e0; e < e1; ++e) {
    int2 c = cw[e];
    float w = __int_as_float(c.y);
    a0 = fmaf(w, h3[(size_t)c.x * 2 + 0], a0);
    a1 = fmaf(w, h3[(size_t)c.x * 2 + 1], a1);
  }
  a0 += b3[0];
  a1 += b3[1];
  float m = fmaxf(a0, a1);
  float lse = m + logf(expf(a0 - m) + expf(a1 - m));
  int g = l2g[i];
  out[(size_t)g * 2 + 0] = a0 - lse;
  out[(size_t)g * 2 + 1] = a1 - lse;
}

// ---------------- launch ----------------

extern "C" void kernel_launch(void* const* d_in, const int* in_sizes, int n_in,
                              void* d_out, int out_size, void* d_ws, size_t ws_size,
                              hipStream_t stream) {
  const float* building_x = (const float*)d_in[0];
  const int*   l2g        = (const int*)d_in[1];
  const int*   esrc       = (const int*)d_in[2];
  const int*   edst       = (const int*)d_in[3];
  const float* W1 = (const float*)d_in[4];
  const float* b1 = (const float*)d_in[5];
  const float* W2 = (const float*)d_in[6];
  const float* b2 = (const float*)d_in[7];
  const float* W3 = (const float*)d_in[8];
  const float* b3 = (const float*)d_in[9];
  float* out = (float*)d_out;

  const int n_total = in_sizes[0] / F_IN;
  const int n_sub   = in_sizes[1];
  const int E       = in_sizes[2];
  const int Etot    = E + n_sub;          // edges + self-loops
  const int nb      = (n_sub + 255) / 256;

  // ---- workspace ----
  char* base = (char*)d_ws;
  auto al = [](size_t x) { return (x + 255) & ~(size_t)255; };
  size_t t128 = al((size_t)n_sub * 128 * 2);
  ushort* xsub = (ushort*)base;                    // layer-1 gather table
  ushort* xt   = (ushort*)(base + t128);           // agg1 out (gemm12 input)
  ushort* h2b  = (ushort*)(base + 2 * t128);       // gemm12 out (layer-2 gather table)
  size_t off = 3 * t128;
  auto alloc = [&](size_t bytes) -> void* {
    void* p = base + off;
    off += al(bytes);
    return p;
  };
  float* h3   = (float*)alloc((size_t)n_sub * 2 * 4);
  int*   cnt  = (int*)alloc((size_t)n_sub * 4);
  int*   fill = (int*)alloc((size_t)n_sub * 4);
  int*   rp   = (int*)alloc((size_t)(n_sub + 1) * 4);
  float* dis  = (float*)alloc((size_t)n_sub * 4);
  int2*  cw   = (int2*)alloc((size_t)Etot * 8);
  int*   bsum = (int*)alloc((size_t)nb * 4);
  ushort* w1f = (ushort*)alloc((size_t)128 * 256 * 2);
  ushort* w2f = (ushort*)alloc((size_t)256 * 128 * 2);
  (void)ws_size; (void)n_in; (void)out_size;

  const int B = 256;

  // zero edge counts (DMA); fused convert + count + weight repack
  hipMemsetAsync(cnt, 0, (size_t)n_sub * 4, stream);
  int prepGrid = ((n_sub * 32 > E ? n_sub * 32 : E) + B - 1) / B;
  k_prep<<<prepGrid, B, 0, stream>>>(building_x, l2g, edst, xsub, cnt,
                                     W1, W2, w1f, w2f, n_sub * 32, E);

  // ordered CSR scans + fill (also pre-fills output with log(1/2))
  k_scan1<<<nb, 256, 0, stream>>>(cnt, rp, bsum, dis, fill, n_sub);
  k_scan2<<<1, 1024, 0, stream>>>(bsum, nb);
  k_scan3<<<(n_sub + B - 1) / B, B, 0, stream>>>(rp, bsum, n_sub, Etot);
  int fillGrid = ((E > 2 * n_total ? E : 2 * n_total) + B - 1) / B;
  k_fill_csr<<<fillGrid, B, 0, stream>>>(esrc, edst, rp, fill, dis, cw, out,
                                         E, n_sub, 2 * n_total);

  const int AB = 512;                      // 8 waves / block (occupancy probe)
  int aggBlocks  = (n_sub + 7) / 8;
  int gemmBlocks = (n_sub + 127) / 128;    // BM=128

  // Layer 1 aggregate (16-deep pipelined gathers) -> bf16 xt
  k_aggb<false, false><<<aggBlocks, AB, 0, stream>>>(xsub, rp, cw, nullptr, nullptr,
                                                     xt, nullptr, n_sub);

  // Layers 1+2 GEMMs fused: h2 = relu(xt@W1+b1)@W2 -> bf16 h2b
  k_gemm12<<<gemmBlocks, 256, 0, stream>>>(xt, w1f, w2f, b1, h2b, n_sub);

  // Layer 2 aggregate + bias + relu + W3 -> h3
  k_aggb<true, true><<<aggBlocks, AB, 0, stream>>>(h2b, rp, cw, b2, W3,
                                                   nullptr, h3, n_sub);

  // Layer 3: aggregate h3 + bias + log_softmax scatter
  k_agg3<<<(n_sub + B - 1) / B, B, 0, stream>>>(h3, rp, cw, b3, l2g, out, n_sub);
}

// Round 15
// 248.546 us; speedup vs baseline: 1.0707x; 1.0707x over previous
//
#include <hip/hip_runtime.h>
#include <hip/hip_bf16.h>

#define F_IN 128

typedef short bf16x8 __attribute__((ext_vector_type(8)));
typedef short bf16x4 __attribute__((ext_vector_type(4)));
typedef float f32x4  __attribute__((ext_vector_type(4)));
typedef float f32x2  __attribute__((ext_vector_type(2)));

// ---------------- W -> fragment-major bf16 repack helper ----------------
// lane l holds W[k = kt*32 + (l>>4)*4 + (j&3) + 16*(j>>2)][col = nt*16 + (l&15)]

template <int KT, int NT>
__device__ inline void prep_w_one(const float* __restrict__ W, ushort* __restrict__ WF,
                                  int tid) {
  int l  = tid & 63;
  int nt = (tid >> 6) % NT;
  int kt = tid / (64 * NT);
  int colc = nt * 16 + (l & 15);
  int kbase = kt * 32 + (l >> 4) * 4;
  ushort v[8];
  #pragma unroll
  for (int j = 0; j < 8; ++j) {
    int k = kbase + (j & 3) + 16 * (j >> 2);
    __hip_bfloat16 h = __float2bfloat16(W[(size_t)k * (NT * 16) + colc]);
    v[j] = *(ushort*)&h;
  }
  uint4 pk;
  pk.x = (uint)v[0] | ((uint)v[1] << 16);
  pk.y = (uint)v[2] | ((uint)v[3] << 16);
  pk.z = (uint)v[4] | ((uint)v[5] << 16);
  pk.w = (uint)v[6] | ((uint)v[7] << 16);
  *(uint4*)(WF + (size_t)tid * 8) = pk;
}

// ---------------- fused: bf16-convert + edge count + weight repack ----------------
// cnt must be zeroed (hipMemsetAsync) before this kernel.

__global__ void k_prep(const float* __restrict__ X, const int* __restrict__ l2g,
                       const int* __restrict__ dst, ushort* __restrict__ xsub,
                       int* __restrict__ cnt,
                       const float* __restrict__ W1, const float* __restrict__ W2,
                       ushort* __restrict__ w1f, ushort* __restrict__ w2f,
                       int n32, int E) {
  int i = blockIdx.x * blockDim.x + threadIdx.x;
  if (i < 4096) prep_w_one<4, 16>(W1, w1f, i);
  else if (i < 8192) prep_w_one<8, 8>(W2, w2f, i - 4096);
  if (i < E) atomicAdd(&cnt[dst[i]], 1);
  if (i < n32) {
    int row = i >> 5, c4 = (i & 31) * 4;
    int g = l2g[row];
    float4 v = *(const float4*)(X + (size_t)g * 128 + c4);
    ushort o[4];
    __hip_bfloat16 h;
    h = __float2bfloat16(v.x); o[0] = *(ushort*)&h;
    h = __float2bfloat16(v.y); o[1] = *(ushort*)&h;
    h = __float2bfloat16(v.z); o[2] = *(ushort*)&h;
    h = __float2bfloat16(v.w); o[3] = *(ushort*)&h;
    uint2 pk;
    pk.x = (uint)o[0] | ((uint)o[1] << 16);
    pk.y = (uint)o[2] | ((uint)o[3] << 16);
    *(uint2*)(xsub + (size_t)row * 128 + c4) = pk;
  }
}

// ---------------- CSR scans (ordered; row size = cnt + 1, self-loop at slot 0) --------

__global__ void k_scan1(const int* __restrict__ cnt, int* __restrict__ rp,
                        int* __restrict__ bsum, float* __restrict__ dis,
                        int* __restrict__ fill, int n) {
  int tid = threadIdx.x;
  int i = blockIdx.x * 256 + tid;
  int v = (i < n) ? cnt[i] + 1 : 0;       // + self-loop
  int orig = v;
  int lane = tid & 63;
  #pragma unroll
  for (int d = 1; d < 64; d <<= 1) {
    int t = __shfl_up(v, d);
    if (lane >= d) v += t;
  }
  __shared__ int wsum[4];
  int wid = tid >> 6;
  if (lane == 63) wsum[wid] = v;
  __syncthreads();
  int off = 0;
  for (int w = 0; w < wid; ++w) off += wsum[w];
  int incl = v + off;
  if (i < n) {
    rp[i]   = incl - orig;
    dis[i]  = rsqrtf((float)orig);
    fill[i] = 1;                          // slot 0 reserved for self
  }
  if (tid == 255) bsum[blockIdx.x] = incl;
}

__global__ void k_scan2(int* __restrict__ bsum, int nb) {
  __shared__ int s[1024];
  int tid = threadIdx.x;
  int v = (tid < nb) ? bsum[tid] : 0;
  s[tid] = v;
  __syncthreads();
  for (int d = 1; d < 1024; d <<= 1) {
    int t = (tid >= d) ? s[tid - d] : 0;
    __syncthreads();
    s[tid] += t;
    __syncthreads();
  }
  if (tid < nb) bsum[tid] = s[tid] - v;
}

__global__ void k_scan3(int* __restrict__ rp, const int* __restrict__ bsum, int n, int Etot) {
  int i = blockIdx.x * blockDim.x + threadIdx.x;
  if (i < n) rp[i] += bsum[i >> 8];
  if (i == 0) rp[n] = Etot;
}

// edges at slots >=1; self (i, dis_i^2) at slot 0; also pre-fills the output tensor
__global__ void k_fill_csr(const int* __restrict__ src, const int* __restrict__ dst,
                           const int* __restrict__ rp, int* __restrict__ fill,
                           const float* __restrict__ dis,
                           int2* __restrict__ cw, float* __restrict__ out,
                           int E, int n, int outtot) {
  int e = blockIdx.x * blockDim.x + threadIdx.x;
  if (e < outtot) out[e] = -0.69314718055994531f;   // log(1/2)
  if (e < n) {
    float d = dis[e];
    cw[rp[e]] = make_int2(e, __float_as_int(d * d));
  }
  if (e < E) {
    int s = src[e], d = dst[e];
    int pos = rp[d] + atomicAdd(&fill[d], 1);
    cw[pos] = make_int2(s, __float_as_int(dis[s] * dis[d]));
  }
}

// ---------------- aggregation: 4 groups x 16 lanes x 16B, 16-deep gather pipeline -----
// One wave per node (256-thread blocks = 4 nodes/block — r13-proven config).
// The node's contiguous cw row sits in registers (lane i = slot i); per-slot (s,w)
// come from __shfl broadcasts. One round covers 16 slots: 4 masked gathers per group
// issued back-to-back BEFORE any FMA (16 rows in flight). Exec-masked guards only.
// FUSEW3 folds the 128x2 GEMM into the epilogue (writes h3[2] instead of the row).

template <bool BIASRELU, bool FUSEW3>
__global__ void k_aggb(const ushort* __restrict__ X, const int* __restrict__ rp,
                       const int2* __restrict__ cw, const float* __restrict__ bias,
                       const float* __restrict__ W3,
                       ushort* __restrict__ outp, float* __restrict__ h3, int n) {
  int wavei = (int)((blockIdx.x * (size_t)blockDim.x + threadIdx.x) >> 6);
  int lane = threadIdx.x & 63;
  if (wavei >= n) return;
  int q = lane >> 4, ln = lane & 15;
  int e0 = rp[wavei], deg = rp[wavei + 1] - e0;  // >= 1 (self at slot 0)
  int dmax = deg < 64 ? deg : 64;

  // whole edge row in registers: lane i holds slot i (coalesced single load)
  int2 cme = make_int2(0, 0);
  if (lane < dmax) cme = cw[e0 + lane];

  f32x2 acc[4];
  #pragma unroll
  for (int j = 0; j < 4; ++j) acc[j] = f32x2{0.f, 0.f};

  for (int t0 = 0; t0 < dmax; t0 += 16) {
    uint4 r[4];
    float wv[4];
    bool  m[4];
    #pragma unroll
    for (int p = 0; p < 4; ++p) {
      int t = t0 + p * 4 + q;
      m[p] = t < dmax;
      int ts = t & 63;
      int  s = __shfl(cme.x, ts);
      wv[p]  = __int_as_float(__shfl(cme.y, ts));
      r[p] = make_uint4(0u, 0u, 0u, 0u);
      if (m[p]) r[p] = *(const uint4*)((const char*)X + (((uint)s << 8) + ((uint)ln << 4)));
    }
    #pragma unroll
    for (int p = 0; p < 4; ++p) {
      if (m[p]) {
        uint u[4] = {r[p].x, r[p].y, r[p].z, r[p].w};
        f32x2 wvv = {wv[p], wv[p]};
        #pragma unroll
        for (int tt = 0; tt < 4; ++tt) {
          f32x2 v;
          v.x = __uint_as_float(u[tt] << 16);
          v.y = __uint_as_float(u[tt] & 0xffff0000u);
          acc[tt] += wvv * v;
        }
      }
    }
  }

  // rare tail: deg > 64 (direct cw reads)
  for (int t0 = 64; t0 < deg; t0 += 4) {
    int t = t0 + q;
    if (t < deg) {
      int2 c = cw[e0 + t];
      float w = __int_as_float(c.y);
      uint4 r = *(const uint4*)((const char*)X + (((uint)c.x << 8) + ((uint)ln << 4)));
      uint u[4] = {r.x, r.y, r.z, r.w};
      f32x2 wvv = {w, w};
      #pragma unroll
      for (int tt = 0; tt < 4; ++tt) {
        f32x2 v;
        v.x = __uint_as_float(u[tt] << 16);
        v.y = __uint_as_float(u[tt] & 0xffff0000u);
        acc[tt] += wvv * v;
      }
    }
  }

  // reduce across the 4 groups (lane bits 4,5)
  #pragma unroll
  for (int j = 0; j < 4; ++j) {
    acc[j].x += __shfl_xor(acc[j].x, 16);
    acc[j].y += __shfl_xor(acc[j].y, 16);
    acc[j].x += __shfl_xor(acc[j].x, 32);
    acc[j].y += __shfl_xor(acc[j].y, 32);
  }

  if (lane < 16) {
    if (BIASRELU) {
      float4 b0 = *(const float4*)(bias + ln * 8);
      float4 b1 = *(const float4*)(bias + ln * 8 + 4);
      acc[0].x = fmaxf(acc[0].x + b0.x, 0.f);
      acc[0].y = fmaxf(acc[0].y + b0.y, 0.f);
      acc[1].x = fmaxf(acc[1].x + b0.z, 0.f);
      acc[1].y = fmaxf(acc[1].y + b0.w, 0.f);
      acc[2].x = fmaxf(acc[2].x + b1.x, 0.f);
      acc[2].y = fmaxf(acc[2].y + b1.y, 0.f);
      acc[3].x = fmaxf(acc[3].x + b1.z, 0.f);
      acc[3].y = fmaxf(acc[3].y + b1.w, 0.f);
    }
    if (FUSEW3) {
      const float4* w3p = (const float4*)(W3 + ln * 16);
      float p0 = 0.f, p1 = 0.f;
      #pragma unroll
      for (int j2 = 0; j2 < 4; ++j2) {
        float4 wa = w3p[j2];
        p0 = fmaf(acc[j2].x, wa.x, p0);
        p1 = fmaf(acc[j2].x, wa.y, p1);
        p0 = fmaf(acc[j2].y, wa.z, p0);
        p1 = fmaf(acc[j2].y, wa.w, p1);
      }
      p0 += __shfl_xor(p0, 1); p1 += __shfl_xor(p1, 1);
      p0 += __shfl_xor(p0, 2); p1 += __shfl_xor(p1, 2);
      p0 += __shfl_xor(p0, 4); p1 += __shfl_xor(p1, 4);
      p0 += __shfl_xor(p0, 8); p1 += __shfl_xor(p1, 8);
      if (ln == 0) {
        float2 rr = make_float2(p0, p1);
        *(float2*)(h3 + (size_t)wavei * 2) = rr;
      }
    } else {
      uint pk[4];
      #pragma unroll
      for (int j2 = 0; j2 < 4; ++j2) {
        __hip_bfloat16 hx = __float2bfloat16(acc[j2].x);
        __hip_bfloat16 hy = __float2bfloat16(acc[j2].y);
        pk[j2] = (uint)(*(ushort*)&hx) | ((uint)(*(ushort*)&hy) << 16);
      }
      uint4 sv = make_uint4(pk[0], pk[1], pk[2], pk[3]);
      *(uint4*)((char*)outp + (((size_t)wavei << 8) + ((uint)ln << 4))) = sv;
    }
  }
}

// ---------------- FUSED GEMM1+GEMM2: xt[n,128] -> h2 = relu(xt@W1+b1)@W2 -> bf16 ------
// Block = 256 threads (4 waves), BM = 128 rows.
// gemm1: wave w owns output cols [w*64, w*64+64) (W1 frags in registers).
// Handoff: those cols ARE gemm2's k-slice (k-tiles 2w, 2w+1); the gemm1 output
// fragment layout equals the gemm2 A-fragment layout.
// gemm2: each wave computes a 16x128 partial (its k-slice) per row-subtile;
// partials summed across the 4 waves via XOR-swizzled LDS, stored bf16.

__global__ __launch_bounds__(256) void k_gemm12(const ushort* __restrict__ A,
                                                const ushort* __restrict__ WF1,
                                                const ushort* __restrict__ WF2,
                                                const float* __restrict__ bias1,
                                                ushort* __restrict__ H2, int n) {
  __shared__ short stage[128 * 128];       // 32 KB bf16 input tile
  __shared__ float red[4][16][128];        // 32 KB f32 partial-sum buffer

  int tid = threadIdx.x;
  int r0 = blockIdx.x * 128;
  int l  = tid & 63;
  int w  = tid >> 6;
  int hi = l >> 4;

  // W1 fragments for this wave's N-slice (cols w*64..w*64+63): nt = w*4..w*4+3
  bf16x8 wreg1[16];
  #pragma unroll
  for (int kt = 0; kt < 4; ++kt)
    #pragma unroll
    for (int nt = 0; nt < 4; ++nt)
      wreg1[kt * 4 + nt] =
          *(const bf16x8*)(WF1 + ((size_t)(kt * 16 + w * 4 + nt) * 64 + l) * 8);

  // W2 fragments for this wave's k-slice (k-tiles 2w, 2w+1), all 8 n-tiles
  bf16x8 wreg2[16];
  #pragma unroll
  for (int kt2 = 0; kt2 < 2; ++kt2)
    #pragma unroll
    for (int nt2 = 0; nt2 < 8; ++nt2)
      wreg2[kt2 * 8 + nt2] =
          *(const bf16x8*)(WF2 + ((size_t)((w * 2 + kt2) * 8 + nt2) * 64 + l) * 8);

  // bias1 for this wave's col slice
  float bb[4][4];
  #pragma unroll
  for (int nt = 0; nt < 4; ++nt) {
    float4 b4 = *(const float4*)(bias1 + (w * 4 + nt) * 16 + hi * 4);
    bb[nt][0] = b4.x; bb[nt][1] = b4.y; bb[nt][2] = b4.z; bb[nt][3] = b4.w;
  }

  // stage xt tile (coalesced 16B loads, XOR-swizzled 16B chunks; 16 chunks/row)
  #pragma unroll
  for (int p = 0; p < 8; ++p) {
    int idx = p * 256 + tid;
    int row = idx >> 4, c = idx & 15;
    uint4 v = make_uint4(0u, 0u, 0u, 0u);
    if (r0 + row < n) v = *(const uint4*)(A + (size_t)(r0 + row) * 128 + c * 8);
    *(uint4*)(&stage[row * 128 + ((c ^ (row & 15)) * 8)]) = v;
  }
  __syncthreads();

  int sw = l & 15;
  for (int s = 0; s < 8; ++s) {
    int rowl = s * 16 + (l & 15);
    // gemm1 X-fragments from LDS
    bf16x8 xf[4];
    #pragma unroll
    for (int kt = 0; kt < 4; ++kt) {
      int c0 = kt * 4 + (hi >> 1);
      int within = (hi & 1) * 4;
      bf16x4 lo = *(const bf16x4*)(&stage[rowl * 128 + (c0 ^ sw) * 8 + within]);
      bf16x4 hx = *(const bf16x4*)(&stage[rowl * 128 + ((c0 + 2) ^ sw) * 8 + within]);
      bf16x8 a;
      a[0] = lo[0]; a[1] = lo[1]; a[2] = lo[2]; a[3] = lo[3];
      a[4] = hx[0]; a[5] = hx[1]; a[6] = hx[2]; a[7] = hx[3];
      xf[kt] = a;
    }

    // gemm1: 16 MFMAs -> acc[nt][r] = h1[row][ (w*4+nt)*16 + hi*4 + r ]
    f32x4 acc[4];
    #pragma unroll
    for (int nt = 0; nt < 4; ++nt) acc[nt] = f32x4{0.f, 0.f, 0.f, 0.f};
    #pragma unroll
    for (int nt = 0; nt < 4; ++nt)
      #pragma unroll
      for (int kt = 0; kt < 4; ++kt)
        acc[nt] = __builtin_amdgcn_mfma_f32_16x16x32_bf16(wreg1[kt * 4 + nt], xf[kt],
                                                          acc[nt], 0, 0, 0);

    // bias + relu + pack: gemm1 output frags ARE gemm2 A-frags for k-tiles 2w,2w+1
    bf16x8 xf2[2];
    #pragma unroll
    for (int kt2 = 0; kt2 < 2; ++kt2) {
      bf16x8 t;
      #pragma unroll
      for (int j = 0; j < 8; ++j) {
        int nt = kt2 * 2 + (j >> 2), r = j & 3;
        float v = fmaxf(acc[nt][r] + bb[nt][r], 0.0f);
        __hip_bfloat16 h = __float2bfloat16(v);
        t[j] = *(short*)&h;
      }
      xf2[kt2] = t;
    }

    // gemm2 partial: 16 MFMAs over this wave's k-slice
    f32x4 acc2[8];
    #pragma unroll
    for (int nt2 = 0; nt2 < 8; ++nt2) acc2[nt2] = f32x4{0.f, 0.f, 0.f, 0.f};
    #pragma unroll
    for (int nt2 = 0; nt2 < 8; ++nt2)
      #pragma unroll
      for (int kt2 = 0; kt2 < 2; ++kt2)
        acc2[nt2] = __builtin_amdgcn_mfma_f32_16x16x32_bf16(wreg2[kt2 * 8 + nt2], xf2[kt2],
                                                            acc2[nt2], 0, 0, 0);

    // write partials to LDS (XOR-swizzled: col ^= (row&7)<<2)
    int prow = l & 15;
    #pragma unroll
    for (int nt2 = 0; nt2 < 8; ++nt2) {
      int col = nt2 * 16 + hi * 4;
      int cs = col ^ ((prow & 7) << 2);
      *(f32x4*)(&red[w][prow][cs]) = acc2[nt2];
    }
    __syncthreads();

    // reduce across 4 waves; store bf16 h2 rows
    #pragma unroll
    for (int gi = 0; gi < 2; ++gi) {
      int g = tid * 2 + gi;
      int row = g >> 5, c4 = (g & 31) * 4;
      int cs = c4 ^ ((row & 7) << 2);
      f32x4 s0 = *(const f32x4*)(&red[0][row][cs]);
      f32x4 s1 = *(const f32x4*)(&red[1][row][cs]);
      f32x4 s2 = *(const f32x4*)(&red[2][row][cs]);
      f32x4 s3 = *(const f32x4*)(&red[3][row][cs]);
      f32x4 sm = s0 + s1 + s2 + s3;
      int grow = r0 + s * 16 + row;
      if (grow < n) {
        ushort o[4];
        __hip_bfloat16 h;
        h = __float2bfloat16(sm[0]); o[0] = *(ushort*)&h;
        h = __float2bfloat16(sm[1]); o[1] = *(ushort*)&h;
        h = __float2bfloat16(sm[2]); o[2] = *(ushort*)&h;
        h = __float2bfloat16(sm[3]); o[3] = *(ushort*)&h;
        uint2 pk;
        pk.x = (uint)o[0] | ((uint)o[1] << 16);
        pk.y = (uint)o[2] | ((uint)o[3] << 16);
        *(uint2*)(H2 + (size_t)grow * 128 + c4) = pk;
      }
    }
    __syncthreads();
  }
}

// ---------------- final: aggregate h3 + bias + log_softmax scatter ----------------

__global__ void k_agg3(const float* __restrict__ h3, const int* __restrict__ rp,
                       const int2* __restrict__ cw, const float* __restrict__ b3,
                       const int* __restrict__ l2g, float* __restrict__ out, int n) {
  int i = blockIdx.x * blockDim.x + threadIdx.x;
  if (i >= n) return;
  float a0 = 0.f, a1 = 0.f;
  int e0 = rp[i], e1 = rp[i + 1];
  for (int e = e0; e < e1; ++e) {
    int2 c = cw[e];
    float w = __int_as_float(c.y);
    a0 = fmaf(w, h3[(size_t)c.x * 2 + 0], a0);
    a1 = fmaf(w, h3[(size_t)c.x * 2 + 1], a1);
  }
  a0 += b3[0];
  a1 += b3[1];
  float m = fmaxf(a0, a1);
  float lse = m + logf(expf(a0 - m) + expf(a1 - m));
  int g = l2g[i];
  out[(size_t)g * 2 + 0] = a0 - lse;
  out[(size_t)g * 2 + 1] = a1 - lse;
}

// ---------------- launch ----------------

extern "C" void kernel_launch(void* const* d_in, const int* in_sizes, int n_in,
                              void* d_out, int out_size, void* d_ws, size_t ws_size,
                              hipStream_t stream) {
  const float* building_x = (const float*)d_in[0];
  const int*   l2g        = (const int*)d_in[1];
  const int*   esrc       = (const int*)d_in[2];
  const int*   edst       = (const int*)d_in[3];
  const float* W1 = (const float*)d_in[4];
  const float* b1 = (const float*)d_in[5];
  const float* W2 = (const float*)d_in[6];
  const float* b2 = (const float*)d_in[7];
  const float* W3 = (const float*)d_in[8];
  const float* b3 = (const float*)d_in[9];
  float* out = (float*)d_out;

  const int n_total = in_sizes[0] / F_IN;
  const int n_sub   = in_sizes[1];
  const int E       = in_sizes[2];
  const int Etot    = E + n_sub;          // edges + self-loops
  const int nb      = (n_sub + 255) / 256;

  // ---- workspace ----
  char* base = (char*)d_ws;
  auto al = [](size_t x) { return (x + 255) & ~(size_t)255; };
  size_t t128 = al((size_t)n_sub * 128 * 2);
  ushort* xsub = (ushort*)base;                    // layer-1 gather table
  ushort* xt   = (ushort*)(base + t128);           // agg1 out (gemm12 input)
  ushort* h2b  = (ushort*)(base + 2 * t128);       // gemm12 out (layer-2 gather table)
  size_t off = 3 * t128;
  auto alloc = [&](size_t bytes) -> void* {
    void* p = base + off;
    off += al(bytes);
    return p;
  };
  float* h3   = (float*)alloc((size_t)n_sub * 2 * 4);
  int*   cnt  = (int*)alloc((size_t)n_sub * 4);
  int*   fill = (int*)alloc((size_t)n_sub * 4);
  int*   rp   = (int*)alloc((size_t)(n_sub + 1) * 4);
  float* dis  = (float*)alloc((size_t)n_sub * 4);
  int2*  cw   = (int2*)alloc((size_t)Etot * 8);
  int*   bsum = (int*)alloc((size_t)nb * 4);
  ushort* w1f = (ushort*)alloc((size_t)128 * 256 * 2);
  ushort* w2f = (ushort*)alloc((size_t)256 * 128 * 2);
  (void)ws_size; (void)n_in; (void)out_size;

  const int B = 256;

  // zero edge counts (DMA); fused convert + count + weight repack
  hipMemsetAsync(cnt, 0, (size_t)n_sub * 4, stream);
  int prepGrid = ((n_sub * 32 > E ? n_sub * 32 : E) + B - 1) / B;
  k_prep<<<prepGrid, B, 0, stream>>>(building_x, l2g, edst, xsub, cnt,
                                     W1, W2, w1f, w2f, n_sub * 32, E);

  // ordered CSR scans + fill (also pre-fills output with log(1/2))
  k_scan1<<<nb, 256, 0, stream>>>(cnt, rp, bsum, dis, fill, n_sub);
  k_scan2<<<1, 1024, 0, stream>>>(bsum, nb);
  k_scan3<<<(n_sub + B - 1) / B, B, 0, stream>>>(rp, bsum, n_sub, Etot);
  int fillGrid = ((E > 2 * n_total ? E : 2 * n_total) + B - 1) / B;
  k_fill_csr<<<fillGrid, B, 0, stream>>>(esrc, edst, rp, fill, dis, cw, out,
                                         E, n_sub, 2 * n_total);

  int aggBlocks  = (n_sub + 3) / 4;       // 4 waves / 256-thread block (r13 config)
  int gemmBlocks = (n_sub + 127) / 128;   // BM=128

  // Layer 1 aggregate (16-deep pipelined gathers) -> bf16 xt
  k_aggb<false, false><<<aggBlocks, B, 0, stream>>>(xsub, rp, cw, nullptr, nullptr,
                                                    xt, nullptr, n_sub);

  // Layers 1+2 GEMMs fused: h2 = relu(xt@W1+b1)@W2 -> bf16 h2b
  k_gemm12<<<gemmBlocks, 256, 0, stream>>>(xt, w1f, w2f, b1, h2b, n_sub);

  // Layer 2 aggregate + bias + relu + W3 -> h3
  k_aggb<true, true><<<aggBlocks, B, 0, stream>>>(h2b, rp, cw, b2, W3,
                                                  nullptr, h3, n_sub);

  // Layer 3: aggregate h3 + bias + log_softmax scatter
  k_agg3<<<(n_sub + B - 1) / B, B, 0, stream>>>(h3, rp, cw, b3, l2g, out, n_sub);
}